// Round 1
// baseline (204.544 us; speedup 1.0000x reference)
//
#include <hip/hip_runtime.h>

// Attn_60705067761886: softmax((enc @ W^T + b) @ h) over S=32768, H=1024, fp32.
//
// Algebra: energies = enc @ (W^T h) + (b.h); the scalar b.h cancels in softmax,
// so we never touch b. Three kernels:
//   K1: v = W^T h            (4 MiB read, split-j blocks + fp32 atomicAdd)
//   K2: e[s] = enc[s] . v    (128 MiB read -- the HBM-bound hot kernel)
//   K3: out = softmax(e)     (single block, registers hold all 32 vals/thread)

#define H 1024
#define S 32768

// ---------------- K1: v = W^T h ----------------
// grid 64 x 256. Block b handles j in [16b, 16b+16); thread t covers
// k = t, t+256, t+512, t+768. Loads of W[j][k] are lane-coalesced.
__global__ __launch_bounds__(256) void matvec_v(const float* __restrict__ W,
                                                const float* __restrict__ h,
                                                float* __restrict__ v) {
    const int t  = threadIdx.x;
    const int j0 = blockIdx.x * 16;
    float a0 = 0.f, a1 = 0.f, a2 = 0.f, a3 = 0.f;
#pragma unroll
    for (int jj = 0; jj < 16; ++jj) {
        const int j = j0 + jj;
        const float hj = h[j];
        const float* Wr = W + (size_t)j * H;
        a0 = fmaf(Wr[t      ], hj, a0);
        a1 = fmaf(Wr[t + 256], hj, a1);
        a2 = fmaf(Wr[t + 512], hj, a2);
        a3 = fmaf(Wr[t + 768], hj, a3);
    }
    atomicAdd(&v[t      ], a0);
    atomicAdd(&v[t + 256], a1);
    atomicAdd(&v[t + 512], a2);
    atomicAdd(&v[t + 768], a3);
}

// ---------------- K2: e[s] = enc[s] . v ----------------
// One wave per 2 rows, 4 waves/block -> 8 rows/block, 4096 blocks.
// Per row: 4x global_load_dwordx4 per lane (64 lanes x 16 B = 1 KiB/instr,
// perfectly coalesced), v fragment preloaded once per wave into registers.
__global__ __launch_bounds__(256) void energies_kernel(const float* __restrict__ enc,
                                                       const float* __restrict__ v,
                                                       float* __restrict__ e) {
    const int wave  = threadIdx.x >> 6;
    const int lane  = threadIdx.x & 63;
    const int lane4 = lane * 4;

    float4 vf[4];
#pragma unroll
    for (int t = 0; t < 4; ++t)
        vf[t] = *(const float4*)(v + t * 256 + lane4);

    const int row0 = (blockIdx.x * 4 + wave) * 2;
#pragma unroll
    for (int r = 0; r < 2; ++r) {
        const int row = row0 + r;
        const float* rp = enc + (size_t)row * H;
        float acc = 0.f;
#pragma unroll
        for (int t = 0; t < 4; ++t) {
            const float4 a = *(const float4*)(rp + t * 256 + lane4);
            acc = fmaf(a.x, vf[t].x, acc);
            acc = fmaf(a.y, vf[t].y, acc);
            acc = fmaf(a.z, vf[t].z, acc);
            acc = fmaf(a.w, vf[t].w, acc);
        }
#pragma unroll
        for (int off = 32; off >= 1; off >>= 1)
            acc += __shfl_down(acc, off, 64);
        if (lane == 0) e[row] = acc;
    }
}

// ---------------- K3: softmax over 32768 ----------------
// Single block, 1024 threads; each thread keeps its 32 energies in registers
// (8 float4), so e is read once. Two block reductions (max, sum) via LDS.
__global__ __launch_bounds__(1024) void softmax_kernel(const float* __restrict__ e,
                                                       float* __restrict__ out) {
    __shared__ float red[16];
    const int t    = threadIdx.x;
    const int lane = t & 63;
    const int wv   = t >> 6;

    float4 x[8];
#pragma unroll
    for (int r = 0; r < 8; ++r)
        x[r] = *(const float4*)(e + 4 * t + 4096 * r);

    float m = -1e30f;
#pragma unroll
    for (int r = 0; r < 8; ++r)
        m = fmaxf(m, fmaxf(fmaxf(x[r].x, x[r].y), fmaxf(x[r].z, x[r].w)));
#pragma unroll
    for (int off = 32; off >= 1; off >>= 1)
        m = fmaxf(m, __shfl_down(m, off, 64));
    if (lane == 0) red[wv] = m;
    __syncthreads();
    if (t < 16) {
        float mm = red[t];
#pragma unroll
        for (int off = 8; off >= 1; off >>= 1)
            mm = fmaxf(mm, __shfl_down(mm, off, 64));
        if (t == 0) red[0] = mm;
    }
    __syncthreads();
    m = red[0];
    __syncthreads();  // red reused below

    float s = 0.f;
#pragma unroll
    for (int r = 0; r < 8; ++r) {
        x[r].x = __expf(x[r].x - m); s += x[r].x;
        x[r].y = __expf(x[r].y - m); s += x[r].y;
        x[r].z = __expf(x[r].z - m); s += x[r].z;
        x[r].w = __expf(x[r].w - m); s += x[r].w;
    }
#pragma unroll
    for (int off = 32; off >= 1; off >>= 1)
        s += __shfl_down(s, off, 64);
    if (lane == 0) red[wv] = s;
    __syncthreads();
    if (t < 16) {
        float ss = red[t];
#pragma unroll
        for (int off = 8; off >= 1; off >>= 1)
            ss += __shfl_down(ss, off, 64);
        if (t == 0) red[0] = ss;
    }
    __syncthreads();
    const float inv = 1.0f / red[0];

#pragma unroll
    for (int r = 0; r < 8; ++r) {
        float4 y;
        y.x = x[r].x * inv;
        y.y = x[r].y * inv;
        y.z = x[r].z * inv;
        y.w = x[r].w * inv;
        *(float4*)(out + 4 * t + 4096 * r) = y;
    }
}

extern "C" void kernel_launch(void* const* d_in, const int* in_sizes, int n_in,
                              void* d_out, int out_size, void* d_ws, size_t ws_size,
                              hipStream_t stream) {
    const float* h   = (const float*)d_in[0];  // [H]
    const float* enc = (const float*)d_in[1];  // [S, H]
    const float* W   = (const float*)d_in[2];  // [H, H]
    // d_in[3] = b: unused -- b.h is constant over S, cancels in softmax.

    float* v = (float*)d_ws;            // H floats
    float* e = (float*)d_ws + H;        // S floats
    float* out = (float*)d_out;         // S floats

    // v is accumulated with atomics; ws is poisoned 0xAA each call -> zero it.
    hipMemsetAsync(v, 0, H * sizeof(float), stream);

    matvec_v<<<64, 256, 0, stream>>>(W, h, v);
    energies_kernel<<<S / 8, 256, 0, stream>>>(enc, v, e);
    softmax_kernel<<<1, 1024, 0, stream>>>(e, out);
}

// Round 2
// 203.411 us; speedup vs baseline: 1.0056x; 1.0056x over previous
//
#include <hip/hip_runtime.h>

// Attn_60705067761886: out = softmax((enc @ W^T + b) @ h), S=32768, H=1024, fp32.
//
// Algebra: energies = enc @ (W^T h) + (b.h); scalar b.h cancels in softmax -> b unused.
// Three dispatches, no atomics, no memset:
//   K1: v = W^T h        (4 MiB, k-split blocks, in-block reduction, direct store)
//   K2: e[s] = enc[s].v  (134 MiB read -- the HBM-bound hot kernel)
//   K3: out = softmax(e) (single block, all values in registers)

#define H 1024
#define S 32768

// ---------------- K1: v[k] = sum_j W[j][k] * h[j] ----------------
// 64 blocks x 256 threads. Block b owns columns k in [16b, 16b+16).
// Thread t: kk = t&15 (column), jj = t>>4 in [0,16) (j residue); loops
// j = 16*i + jj for i in [0,64). One wave's load instruction touches
// 4 j-rows x 16 consecutive k = 4 full 64B cachelines (100% utilization).
// Reduce: shfl_xor over lane bits 4,5 (within-wave jj), LDS across 4 waves.
__global__ __launch_bounds__(256) void matvec_v(const float* __restrict__ W,
                                                const float* __restrict__ h,
                                                float* __restrict__ v) {
    __shared__ float sh[64];
    const int t    = threadIdx.x;
    const int kk   = t & 15;
    const int jj   = t >> 4;          // 0..15 across the block
    const int w    = t >> 6;
    const int lane = t & 63;
    const int k0   = blockIdx.x * 16;

    const float* Wp = W + (size_t)jj * H + k0 + kk;  // advances by 16 rows/iter
    float a0 = 0.f, a1 = 0.f;
#pragma unroll
    for (int i = 0; i < 64; i += 2) {
        a0 = fmaf(Wp[(size_t)(16 * i) * H],       h[16 * i + jj],       a0);
        a1 = fmaf(Wp[(size_t)(16 * (i + 1)) * H], h[16 * (i + 1) + jj], a1);
    }
    float a = a0 + a1;
    a += __shfl_xor(a, 16, 64);
    a += __shfl_xor(a, 32, 64);
    if (lane < 16) sh[w * 16 + lane] = a;
    __syncthreads();
    if (t < 16) v[k0 + t] = sh[t] + sh[t + 16] + sh[t + 32] + sh[t + 48];
}

// ---------------- K2: e[s] = enc[s] . v ----------------
// 2048 blocks x 256 threads; wave handles 4 consecutive rows. All 16
// global_load_dwordx4 (64 lanes x 16 B = 1 KiB each, perfectly coalesced)
// are issued before the FMA chains for max memory-level parallelism.
// v fragment (16 floats/lane) loaded once per wave.
__global__ __launch_bounds__(256) void energies_kernel(const float* __restrict__ enc,
                                                       const float* __restrict__ v,
                                                       float* __restrict__ e) {
    const int wave  = threadIdx.x >> 6;
    const int lane  = threadIdx.x & 63;
    const int lane4 = lane * 4;

    float4 vf[4];
#pragma unroll
    for (int t = 0; t < 4; ++t)
        vf[t] = *(const float4*)(v + t * 256 + lane4);

    const int row0 = (blockIdx.x * 4 + wave) * 4;
    const float* rp = enc + (size_t)row0 * H + lane4;

    float4 a[4][4];
#pragma unroll
    for (int r = 0; r < 4; ++r)
#pragma unroll
        for (int t = 0; t < 4; ++t)
            a[r][t] = *(const float4*)(rp + (size_t)r * H + t * 256);

    float acc[4];
#pragma unroll
    for (int r = 0; r < 4; ++r) {
        float s = 0.f;
#pragma unroll
        for (int t = 0; t < 4; ++t) {
            s = fmaf(a[r][t].x, vf[t].x, s);
            s = fmaf(a[r][t].y, vf[t].y, s);
            s = fmaf(a[r][t].z, vf[t].z, s);
            s = fmaf(a[r][t].w, vf[t].w, s);
        }
#pragma unroll
        for (int off = 32; off >= 1; off >>= 1)
            s += __shfl_xor(s, off, 64);
        acc[r] = s;
    }
    if (lane == 0)
        *(float4*)(e + row0) = make_float4(acc[0], acc[1], acc[2], acc[3]);
}

// ---------------- K3: softmax over 32768 ----------------
// Single block, 1024 threads; each thread keeps its 32 energies in registers.
__global__ __launch_bounds__(1024) void softmax_kernel(const float* __restrict__ e,
                                                       float* __restrict__ out) {
    __shared__ float red[16];
    const int t    = threadIdx.x;
    const int lane = t & 63;
    const int wv   = t >> 6;

    float4 x[8];
#pragma unroll
    for (int r = 0; r < 8; ++r)
        x[r] = *(const float4*)(e + 4 * t + 4096 * r);

    float m = -1e30f;
#pragma unroll
    for (int r = 0; r < 8; ++r)
        m = fmaxf(m, fmaxf(fmaxf(x[r].x, x[r].y), fmaxf(x[r].z, x[r].w)));
#pragma unroll
    for (int off = 32; off >= 1; off >>= 1)
        m = fmaxf(m, __shfl_xor(m, off, 64));
    if (lane == 0) red[wv] = m;
    __syncthreads();
    if (t < 16) {
        float mm = red[t];
#pragma unroll
        for (int off = 8; off >= 1; off >>= 1)
            mm = fmaxf(mm, __shfl_xor(mm, off, 64));
        if (t == 0) red[0] = mm;
    }
    __syncthreads();
    m = red[0];
    __syncthreads();  // red reused below

    float s = 0.f;
#pragma unroll
    for (int r = 0; r < 8; ++r) {
        x[r].x = __expf(x[r].x - m); s += x[r].x;
        x[r].y = __expf(x[r].y - m); s += x[r].y;
        x[r].z = __expf(x[r].z - m); s += x[r].z;
        x[r].w = __expf(x[r].w - m); s += x[r].w;
    }
#pragma unroll
    for (int off = 32; off >= 1; off >>= 1)
        s += __shfl_xor(s, off, 64);
    if (lane == 0) red[wv] = s;
    __syncthreads();
    if (t < 16) {
        float ss = red[t];
#pragma unroll
        for (int off = 8; off >= 1; off >>= 1)
            ss += __shfl_xor(ss, off, 64);
        if (t == 0) red[0] = ss;
    }
    __syncthreads();
    const float inv = 1.0f / red[0];

#pragma unroll
    for (int r = 0; r < 8; ++r) {
        float4 y;
        y.x = x[r].x * inv;
        y.y = x[r].y * inv;
        y.z = x[r].z * inv;
        y.w = x[r].w * inv;
        *(float4*)(out + 4 * t + 4096 * r) = y;
    }
}

extern "C" void kernel_launch(void* const* d_in, const int* in_sizes, int n_in,
                              void* d_out, int out_size, void* d_ws, size_t ws_size,
                              hipStream_t stream) {
    const float* h   = (const float*)d_in[0];  // [H]
    const float* enc = (const float*)d_in[1];  // [S, H]
    const float* W   = (const float*)d_in[2];  // [H, H]
    // d_in[3] = b: unused -- b.h is constant over S, cancels in softmax.

    float* v = (float*)d_ws;       // H floats
    float* e = (float*)d_ws + H;   // S floats
    float* out = (float*)d_out;    // S floats

    matvec_v<<<64, 256, 0, stream>>>(W, h, v);
    energies_kernel<<<S / 16, 256, 0, stream>>>(enc, v, e);
    softmax_kernel<<<1, 1024, 0, stream>>>(e, out);
}